// Round 1
// baseline (4793.081 us; speedup 1.0000x reference)
//
#include <hip/hip_runtime.h>
#include <hip/hip_bf16.h>
#include <stdint.h>

// Problem constants (VanillaRNN): B=64, T=4096, D=256, H=256, O=256, all fp32.
#define TT 4096
#define BBATCH 64
#define DD 256
#define HH 256
#define OO 256

typedef float  f32x4  __attribute__((ext_vector_type(4)));
typedef short  bf16x8 __attribute__((ext_vector_type(8)));

__device__ __forceinline__ unsigned short f2bf(float f) {
  unsigned u = __float_as_uint(f);
  u += 0x7FFFu + ((u >> 16) & 1u);   // RNE; inputs are finite
  return (unsigned short)(u >> 16);
}
__device__ __forceinline__ float bf2f(unsigned short h) {
  return __uint_as_float(((unsigned)h) << 16);
}

// ---------------------------------------------------------------------------
// K0: Wt[n][k] = bf16(W[k][n]) for W_xh and W_hy (tiny; makes MFMA B-fragment
// loads 16B-contiguous per lane).
// ---------------------------------------------------------------------------
__global__ void k0_transpose(const float* __restrict__ Wxh, const float* __restrict__ Why,
                             unsigned short* __restrict__ Wt1, unsigned short* __restrict__ Wt2) {
  const int n = blockIdx.x & 255;
  const int k = threadIdx.x;
  if (blockIdx.x < 256) Wt1[n * 256 + k] = f2bf(Wxh[k * 256 + n]);
  else                  Wt2[n * 256 + k] = f2bf(Why[k * 256 + n]);
}

// ---------------------------------------------------------------------------
// K1: xp[t][b][h] = bf16( x[b][t][:] @ W_xh[:,h] + b_h[h] )
// Block: 256 thr (4 waves), M-tile = 64 rows (one b, 64 consecutive t),
// N = 256 (wave nt-chunk = 64 cols), K = 256. bf16 MFMA 16x16x32.
// A staged in LDS (f32 -> bf16), pad +8 bf16/row -> <=2-way bank aliasing.
// W fragments preloaded to registers once per block (L2-resident 128KB).
// ---------------------------------------------------------------------------
__global__ __launch_bounds__(256) void k1_gemm_xp(
    const float* __restrict__ x, const unsigned short* __restrict__ Wt,
    const float* __restrict__ bh, unsigned short* __restrict__ xp) {
  __shared__ __align__(16) unsigned short As[64 * 264];
  const int tid = threadIdx.x;
  const int m0 = blockIdx.x * 64;              // global row m = b*4096 + t

  // stage A tile: 64 rows x 256 f32 -> bf16 LDS (coalesced dwordx4 loads)
  #pragma unroll
  for (int rr = 0; rr < 16; ++rr) {
    int idx = tid + rr * 256;                  // 0..4095
    int row = idx >> 6;
    int c4  = (idx & 63) << 2;
    f32x4 v = *(const f32x4*)(x + (size_t)(m0 + row) * 256 + c4);
    unsigned w0 = (unsigned)f2bf(v[0]) | ((unsigned)f2bf(v[1]) << 16);
    unsigned w1 = (unsigned)f2bf(v[2]) | ((unsigned)f2bf(v[3]) << 16);
    *(uint2*)(As + row * 264 + c4) = make_uint2(w0, w1);
  }

  const int wv = tid >> 6, ln = tid & 63, l15 = ln & 15, q = ln >> 4;

  // preload B fragments: wave wv covers nt = 4wv..4wv+3 (16 cols each), 8 K-tiles
  bf16x8 bfr[4][8];
  #pragma unroll
  for (int ntl = 0; ntl < 4; ++ntl) {
    #pragma unroll
    for (int kt = 0; kt < 8; ++kt) {
      int n = (wv * 4 + ntl) * 16 + l15;
      int k = kt * 32 + q * 8;
      bfr[ntl][kt] = *(const bf16x8*)(Wt + n * 256 + k);
    }
  }
  float biasv[4];
  #pragma unroll
  for (int ntl = 0; ntl < 4; ++ntl) biasv[ntl] = bh[(wv * 4 + ntl) * 16 + l15];

  __syncthreads();

  #pragma unroll 1
  for (int ms = 0; ms < 4; ++ms) {
    bf16x8 afr[8];
    #pragma unroll
    for (int kt = 0; kt < 8; ++kt)
      afr[kt] = *(const bf16x8*)(As + (ms * 16 + l15) * 264 + kt * 32 + q * 8);
    f32x4 acc[4];
    #pragma unroll
    for (int ntl = 0; ntl < 4; ++ntl) acc[ntl] = (f32x4){0.f, 0.f, 0.f, 0.f};
    #pragma unroll
    for (int ntl = 0; ntl < 4; ++ntl) {
      #pragma unroll
      for (int kt = 0; kt < 8; ++kt)
        acc[ntl] = __builtin_amdgcn_mfma_f32_16x16x32_bf16(afr[kt], bfr[ntl][kt], acc[ntl], 0, 0, 0);
    }
    // C layout: col = lane&15, row = 4*(lane>>4) + reg  [m89]
    #pragma unroll
    for (int ntl = 0; ntl < 4; ++ntl) {
      int c = (wv * 4 + ntl) * 16 + l15;
      #pragma unroll
      for (int r = 0; r < 4; ++r) {
        int m = m0 + ms * 16 + q * 4 + r;
        int t = m & 4095, b = m >> 12;
        xp[(size_t)(t * 64 + b) * 256 + c] = f2bf(acc[ntl][r] + biasv[ntl]);
      }
    }
  }
}

// ---------------------------------------------------------------------------
// K2: sequential recurrence. One WG per batch row (64 WGs x 512 thr, 8 waves).
// W_hh fully in registers: thread (ig=tid>>6, jg=tid&63) holds
// W_hh[32ig..32ig+32)[4jg..4jg+4) = 128 VGPRs. Per step: wave reads its 32
// h values with ONE ds_read (lane l -> h[32ig + (l&31)]), then 32 readlane
// broadcasts feed 128 FMAs. 8 partials/column reduced via LDS by waves 0-3.
// xp (bf16) is read and hs (bf16) written IN PLACE in the same buffer
// (row t*64+b written at step t; row (t+1)*64+b read at step t -> disjoint).
// ---------------------------------------------------------------------------
__global__ __launch_bounds__(512) void k2_rnn(
    unsigned short* xp_hs,                     // aliased: xp in, hs out (bf16)
    const float* __restrict__ h0, const float* __restrict__ Whh,
    float* __restrict__ hfin) {
  __shared__ float hbuf[256];
  __shared__ float part[8][256];
  const int tid = threadIdx.x;
  const int b   = blockIdx.x;
  const int ig  = tid >> 6;                    // wave id: i in [32ig, 32ig+32)
  const int jg  = tid & 63;                    // columns 4jg..4jg+3

  float w[32][4];
  #pragma unroll
  for (int i = 0; i < 32; ++i)
    *(f32x4*)w[i] = *(const f32x4*)(Whh + (size_t)(32 * ig + i) * 256 + 4 * jg);

  float xpv = 0.f;
  if (tid < 256) {
    hbuf[tid] = h0[b * 256 + tid];
    xpv = bf2f(xp_hs[(size_t)b * 256 + tid]);  // xp[t=0]
  }
  __syncthreads();

  #pragma unroll 1
  for (int t = 0; t < 4096; ++t) {
    float hv = hbuf[32 * ig + (tid & 31)];     // one LDS read per wave-chunk
    float a0 = 0.f, a1 = 0.f, a2 = 0.f, a3 = 0.f;
    #pragma unroll
    for (int i = 0; i < 32; ++i) {
      float s = __uint_as_float((unsigned)__builtin_amdgcn_readlane(__float_as_uint(hv), i));
      a0 = fmaf(s, w[i][0], a0);
      a1 = fmaf(s, w[i][1], a1);
      a2 = fmaf(s, w[i][2], a2);
      a3 = fmaf(s, w[i][3], a3);
    }
    *(f32x4*)&part[ig][4 * jg] = (f32x4){a0, a1, a2, a3};
    __syncthreads();
    if (tid < 256) {
      float s = part[0][tid] + part[1][tid] + part[2][tid] + part[3][tid]
              + part[4][tid] + part[5][tid] + part[6][tid] + part[7][tid] + xpv;
      float e  = __expf(2.f * s);              // tanh(x) = 1 - 2/(e^{2x}+1)
      float hn = 1.f - 2.f / (e + 1.f);
      hbuf[tid] = hn;
      xp_hs[(size_t)(t * 64 + b) * 256 + tid] = f2bf(hn);          // hs[t]
      if (t < 4095)
        xpv = bf2f(xp_hs[(size_t)((t + 1) * 64 + b) * 256 + tid]); // prefetch xp[t+1]
    }
    __syncthreads();
  }
  if (tid < 256) hfin[b * 256 + tid] = hbuf[tid];
}

// ---------------------------------------------------------------------------
// K3: out[b][t][o] = hs[t][b][:] @ W_hy[:,o] + b_y[o]   (f32 out)
// Same skeleton as K1; A input already bf16.
// ---------------------------------------------------------------------------
__global__ __launch_bounds__(256) void k3_gemm_out(
    const unsigned short* __restrict__ hs, const unsigned short* __restrict__ Wt,
    const float* __restrict__ by, float* __restrict__ out) {
  __shared__ __align__(16) unsigned short As[64 * 264];
  const int tid = threadIdx.x;
  const int m0 = blockIdx.x * 64;              // row m = t*64 + b

  #pragma unroll
  for (int rr = 0; rr < 8; ++rr) {
    int idx = tid + rr * 256;                  // 0..2047
    int row = idx >> 5;
    int c8  = (idx & 31) << 3;
    *(uint4*)(As + row * 264 + c8) = *(const uint4*)(hs + (size_t)(m0 + row) * 256 + c8);
  }

  const int wv = tid >> 6, ln = tid & 63, l15 = ln & 15, q = ln >> 4;

  bf16x8 bfr[4][8];
  #pragma unroll
  for (int ntl = 0; ntl < 4; ++ntl) {
    #pragma unroll
    for (int kt = 0; kt < 8; ++kt) {
      int n = (wv * 4 + ntl) * 16 + l15;
      int k = kt * 32 + q * 8;
      bfr[ntl][kt] = *(const bf16x8*)(Wt + n * 256 + k);
    }
  }
  float biasv[4];
  #pragma unroll
  for (int ntl = 0; ntl < 4; ++ntl) biasv[ntl] = by[(wv * 4 + ntl) * 16 + l15];

  __syncthreads();

  #pragma unroll 1
  for (int ms = 0; ms < 4; ++ms) {
    bf16x8 afr[8];
    #pragma unroll
    for (int kt = 0; kt < 8; ++kt)
      afr[kt] = *(const bf16x8*)(As + (ms * 16 + l15) * 264 + kt * 32 + q * 8);
    f32x4 acc[4];
    #pragma unroll
    for (int ntl = 0; ntl < 4; ++ntl) acc[ntl] = (f32x4){0.f, 0.f, 0.f, 0.f};
    #pragma unroll
    for (int ntl = 0; ntl < 4; ++ntl) {
      #pragma unroll
      for (int kt = 0; kt < 8; ++kt)
        acc[ntl] = __builtin_amdgcn_mfma_f32_16x16x32_bf16(afr[kt], bfr[ntl][kt], acc[ntl], 0, 0, 0);
    }
    #pragma unroll
    for (int ntl = 0; ntl < 4; ++ntl) {
      int c = (wv * 4 + ntl) * 16 + l15;
      #pragma unroll
      for (int r = 0; r < 4; ++r) {
        int m  = m0 + ms * 16 + q * 4 + r;
        int bb = m & 63, t = m >> 6;
        out[(size_t)(bb * 4096 + t) * 256 + c] = acc[ntl][r] + biasv[ntl];
      }
    }
  }
}

// ---------------------------------------------------------------------------
extern "C" void kernel_launch(void* const* d_in, const int* in_sizes, int n_in,
                              void* d_out, int out_size, void* d_ws, size_t ws_size,
                              hipStream_t stream) {
  const float* x   = (const float*)d_in[0];
  const float* h0  = (const float*)d_in[1];
  const float* Wxh = (const float*)d_in[2];
  const float* Whh = (const float*)d_in[3];
  const float* bh  = (const float*)d_in[4];
  const float* Why = (const float*)d_in[5];
  const float* by  = (const float*)d_in[6];
  float* out = (float*)d_out;

  // workspace: [xp/hs bf16 : T*B*H][Wt1 bf16 64K][Wt2 bf16 64K]  (~134.5 MB)
  unsigned short* xp  = (unsigned short*)d_ws;
  unsigned short* Wt1 = xp + (size_t)TT * BBATCH * HH;
  unsigned short* Wt2 = Wt1 + 256 * 256;
  float* hfin = out + (size_t)BBATCH * TT * OO;

  hipLaunchKernelGGL(k0_transpose, dim3(512), dim3(256), 0, stream, Wxh, Why, Wt1, Wt2);
  hipLaunchKernelGGL(k1_gemm_xp,  dim3(4096), dim3(256), 0, stream, x, Wt1, bh, xp);
  hipLaunchKernelGGL(k2_rnn,      dim3(64),   dim3(512), 0, stream, xp, h0, Whh, hfin);
  hipLaunchKernelGGL(k3_gemm_out, dim3(4096), dim3(256), 0, stream, xp, Wt2, by, out);
}